// Round 4
// baseline (5524.421 us; speedup 1.0000x reference)
//
#include <hip/hip_runtime.h>

#define N_CLOUDS 16
#define PTS      16384
#define M        4096
#define FPS_THREADS  1024
#define NWAVES   (FPS_THREADS / 64)   // 16 waves
#define PPT      16                   // consecutive (sorted-order) points per thread
#define SORT_THREADS 512

typedef float v2f __attribute__((ext_vector_type(2)));
typedef unsigned long long u64;
typedef unsigned int u32;
typedef unsigned short u16;

// Round-9: Morton-order tiles -> compact 3D wave regions + 3D exact prune.
//  - sort_kernel: ONE full bitonic over (morton18<<14)|orig keys (6 bits per
//    dim, zyx interleave). Contiguous 1024-pt sorted ranges = compact 3D
//    octree regions: tight bounds in ALL dims (round-8's 4x4 xy tiles spanned
//    full z, inflating wave maxDD via sparse z-tail stragglers -> only ~9/16
//    waves pruned; Morton fixes the z dimension AND drops the 2nd bitonic
//    pass that cost ~230us).
//  - fps_kernel: wave bbox now TRUE 3D min/max of its registers; prune
//    lb = (dxg^2+dyg^2+dzg^2)*0.9999 > cached wave maxDD (provable bit-exact
//    no-op; fp err ~4e-7 << 1e-4 margin). Winner's wave always active.
//  - exactness unchanged: u64 key = (dist_bits<<32)|~orig, per-16-chunk
//    ascending-orig slots, first-occurrence argmax ties bit-identical.

#define PAIRS8_X(X) X(0) X(1) X(2) X(3) X(4) X(5) X(6) X(7)

// u64 max-combine with DPP-shifted copy (old=0 is identity: keys >= 0)
#define DPP_MAX_STEP(key, CTRL) { \
        const u32 lo_  = (u32)(key); \
        const u32 hi_  = (u32)((key) >> 32); \
        const u32 lo2_ = (u32)__builtin_amdgcn_update_dpp(0, (int)lo_, (CTRL), 0xf, 0xf, false); \
        const u32 hi2_ = (u32)__builtin_amdgcn_update_dpp(0, (int)hi_, (CTRL), 0xf, 0xf, false); \
        const u64 ok_  = ((u64)hi2_ << 32) | lo2_; \
        (key) = (ok_ > (key)) ? ok_ : (key); \
    }

// float min/max wave-reduce step; old = own value (identity for masked lanes)
#define DPP_FMIN_STEP(v, CTRL) { \
        const int t_ = __builtin_amdgcn_update_dpp(__float_as_int(v), __float_as_int(v), (CTRL), 0xf, 0xf, false); \
        (v) = fminf((v), __int_as_float(t_)); \
    }
#define DPP_FMAX_STEP(v, CTRL) { \
        const int t_ = __builtin_amdgcn_update_dpp(__float_as_int(v), __float_as_int(v), (CTRL), 0xf, 0xf, false); \
        (v) = fmaxf((v), __int_as_float(t_)); \
    }
#define DPP_RED6(MACRO, v) \
        MACRO(v, 0x111) MACRO(v, 0x112) MACRO(v, 0x114) MACRO(v, 0x118) \
        MACRO(v, 0x142) MACRO(v, 0x143)

__device__ __forceinline__ u32 spread3(u32 v) {   // 6 bits -> every 3rd bit
    u32 r = (v & 1u);
    r |= (v & 2u)  << 2;
    r |= (v & 4u)  << 4;
    r |= (v & 8u)  << 6;
    r |= (v & 16u) << 8;
    r |= (v & 32u) << 10;
    return r;
}

// ---------------------------------------------------------------------------
// One-time spatial ordering kernel: one block per cloud.
// Keys (morton18 << 14) | orig_idx; one full bitonic; per-16-chunk re-sort
// ascending by ORIGINAL index; emit reordered coords + slot-major u16 map.
// fps correctness does NOT depend on sort quality (map is a permutation);
// sort quality only affects pruning rate.
// ---------------------------------------------------------------------------
__global__ __launch_bounds__(SORT_THREADS)
void sort_kernel(const float* __restrict__ pos, float* __restrict__ pos_s,
                 u16* __restrict__ mapT)
{
    __shared__ u32 keys[PTS];          // 64 KiB
    const int cloud = blockIdx.x;
    const int tid   = threadIdx.x;
    const int ln    = tid & 63;
    const size_t b3 = (size_t)cloud * PTS * 3;

    // ---- x/y/z ranges of this cloud ----
    float mnx = 1e30f, mxx = -1e30f, mny = 1e30f, mxy = -1e30f;
    float mnz = 1e30f, mxz = -1e30f;
    for (int s = 0; s < PTS / SORT_THREADS; ++s) {
        const size_t o = b3 + (size_t)(tid + s * SORT_THREADS) * 3;
        const float x = pos[o + 0];
        const float y = pos[o + 1];
        const float z = pos[o + 2];
        mnx = fminf(mnx, x); mxx = fmaxf(mxx, x);
        mny = fminf(mny, y); mxy = fmaxf(mxy, y);
        mnz = fminf(mnz, z); mxz = fmaxf(mxz, z);
    }
    DPP_RED6(DPP_FMIN_STEP, mnx)
    DPP_RED6(DPP_FMAX_STEP, mxx)
    DPP_RED6(DPP_FMIN_STEP, mny)
    DPP_RED6(DPP_FMAX_STEP, mxy)
    DPP_RED6(DPP_FMIN_STEP, mnz)
    DPP_RED6(DPP_FMAX_STEP, mxz)
    float* red = (float*)keys;         // reuse LDS before keys are written
    const int nw = SORT_THREADS / 64;
    if (ln == 63) {
        red[tid >> 6]          = mnx;
        red[nw + (tid >> 6)]   = mxx;
        red[2*nw + (tid >> 6)] = mny;
        red[3*nw + (tid >> 6)] = mxy;
        red[4*nw + (tid >> 6)] = mnz;
        red[5*nw + (tid >> 6)] = mxz;
    }
    __syncthreads();
    float xmin = red[0], xmax = red[nw], ymin = red[2*nw], ymax = red[3*nw];
    float zmin = red[4*nw], zmax = red[5*nw];
    for (int w = 1; w < nw; ++w) {
        xmin = fminf(xmin, red[w]);
        xmax = fmaxf(xmax, red[nw + w]);
        ymin = fminf(ymin, red[2*nw + w]);
        ymax = fmaxf(ymax, red[3*nw + w]);
        zmin = fminf(zmin, red[4*nw + w]);
        zmax = fmaxf(zmax, red[5*nw + w]);
    }
    __syncthreads();

    // ---- Morton keys: 18-bit zyx-interleaved | 14-bit orig index ----
    const float xscale = 63.999f / fmaxf(xmax - xmin, 1e-30f);
    const float yscale = 63.999f / fmaxf(ymax - ymin, 1e-30f);
    const float zscale = 63.999f / fmaxf(zmax - zmin, 1e-30f);
    for (int s = 0; s < PTS / SORT_THREADS; ++s) {
        const int i = tid + s * SORT_THREADS;
        const size_t o = b3 + (size_t)i * 3;
        const u32 qx = (u32)fminf(fmaxf((pos[o + 0] - xmin) * xscale, 0.0f), 63.0f);
        const u32 qy = (u32)fminf(fmaxf((pos[o + 1] - ymin) * yscale, 0.0f), 63.0f);
        const u32 qz = (u32)fminf(fmaxf((pos[o + 2] - zmin) * zscale, 0.0f), 63.0f);
        const u32 m = spread3(qx) | (spread3(qy) << 1) | (spread3(qz) << 2);
        keys[i] = (m << 14) | (u32)i;
    }

    // ---- one full bitonic sort of 16384 u32 keys in LDS ----
    for (u32 k = 2; k <= (u32)PTS; k <<= 1) {
        for (u32 j = k >> 1; j; j >>= 1) {
            __syncthreads();
            for (int s = 0; s < PTS / SORT_THREADS; ++s) {
                const u32 i = (u32)(tid + s * SORT_THREADS);
                const u32 p = i ^ j;
                if (p > i) {
                    const u32 a = keys[i], b = keys[p];
                    if (((i & k) == 0) == (a > b)) { keys[i] = b; keys[p] = a; }
                }
            }
        }
    }
    __syncthreads();

    // ---- within each 16-chunk (one fps thread's slots), re-sort ascending
    //      by ORIGINAL index -> exact first-occurrence tie semantics ----
    for (int c = 0; c < 2; ++c) {
        u32 loc[PPT];
        const int cb = tid * 32 + c * PPT;
        for (int s = 0; s < PPT; ++s) loc[s] = keys[cb + s] & (u32)(PTS - 1);
        for (int a = 1; a < PPT; ++a) {
            const u32 v = loc[a];
            int b = a;
            while (b > 0 && loc[b - 1] > v) { loc[b] = loc[b - 1]; --b; }
            loc[b] = v;
        }
        for (int s = 0; s < PPT; ++s) keys[cb + s] = loc[s];
    }
    __syncthreads();

    // ---- emit reordered coords (bit-copies) + slot-major map [16][1024] ----
    for (int s = 0; s < PTS / SORT_THREADS; ++s) {
        const int i = tid + s * SORT_THREADS;   // sorted position
        const u32 orig = keys[i];
        mapT[(size_t)cloud * PTS + (size_t)(i & (PPT - 1)) * FPS_THREADS + (i >> 4)] = (u16)orig;
        const size_t so = b3 + (size_t)i * 3;
        const size_t oo = b3 + (size_t)orig * 3;
        pos_s[so + 0] = pos[oo + 0];
        pos_s[so + 1] = pos[oo + 1];
        pos_s[so + 2] = pos[oo + 2];
    }
}

// ---------------------------------------------------------------------------
// Main FPS kernel (one block per cloud, 16 waves). SORTED=false fallback.
// ---------------------------------------------------------------------------
template<bool SORTED>
__global__ __launch_bounds__(FPS_THREADS)
__attribute__((amdgpu_waves_per_eu(4, 4)))
void fps_kernel(const float* __restrict__ pos,      // original (winner fetch, q0)
                const float* __restrict__ psrc,     // sorted coords (or == pos)
                const u16* __restrict__ mapT,       // slot-major orig map (or null)
                int* __restrict__ out)
{
#pragma clang fp contract(off)
    const int cloud = blockIdx.x;
    const int tid   = threadIdx.x;
    const int base  = cloud * PTS;
    const int wave  = tid >> 6;
    const int lane  = tid & 63;

    __shared__ u64 skey[2][NWAVES];
    __shared__ __attribute__((aligned(16))) u16 mlds[PTS];   // [slot][thread]

    if constexpr (SORTED) {
        // stage orig-index map into LDS (coalesced uint4 copy)
        const uint4* src = (const uint4*)(mapT + (size_t)cloud * PTS);
        uint4* dst = (uint4*)mlds;
#pragma unroll
        for (int s = 0; s < PTS * 2 / 16 / FPS_THREADS; ++s)   // 2 iters
            dst[s * FPS_THREADS + tid] = src[s * FPS_THREADS + tid];
        __syncthreads();
    }

    // ---- query = point 0 of cloud (ORIGINAL order) ----
    const float q0x = pos[(size_t)base * 3 + 0];
    const float q0y = pos[(size_t)base * 3 + 1];
    const float q0z = pos[(size_t)base * 3 + 2];
    v2f qx2 = {q0x, q0x}, qy2 = {q0y, q0y}, qz2 = {q0z, q0z};

    // ---- one-time vectorized load: 16 consecutive pts = 12 float4,
    //      loaded per-quad (3 float4 -> 6 v2f) to cap VGPR pressure ----
    const float4* pos4 = (const float4*)psrc;
    const int fo = cloud * (PTS * 3 / 4) + tid * (PPT * 3 / 4);   // 12 f4/thread

#define DECL(j) v2f XX##j, YY##j, ZZ##j, DD##j;
    PAIRS8_X(DECL)
#undef DECL

#define QUADLOAD(q, j0, j1) { \
        const float4 fa = pos4[fo + 3*(q) + 0]; \
        const float4 fb = pos4[fo + 3*(q) + 1]; \
        const float4 fc = pos4[fo + 3*(q) + 2]; \
        XX##j0 = (v2f){fa.x, fa.w}; \
        YY##j0 = (v2f){fa.y, fb.x}; \
        ZZ##j0 = (v2f){fa.z, fb.y}; \
        XX##j1 = (v2f){fb.z, fc.y}; \
        YY##j1 = (v2f){fb.w, fc.z}; \
        ZZ##j1 = (v2f){fc.x, fc.w}; }
    QUADLOAD(0, 0, 1) QUADLOAD(1, 2, 3) QUADLOAD(2, 4, 5) QUADLOAD(3, 6, 7)
#undef QUADLOAD

    // ---- pin coords in VGPRs: opaque defs => no remat, no reload ----
#define PIN8(a,b,c,d,e,g,h,k) asm volatile("" : "+v"(a),"+v"(b),"+v"(c),"+v"(d),"+v"(e),"+v"(g),"+v"(h),"+v"(k));
    PIN8(XX0, XX1, XX2, XX3, XX4, XX5, XX6, XX7)
    PIN8(YY0, YY1, YY2, YY3, YY4, YY5, YY6, YY7)
    PIN8(ZZ0, ZZ1, ZZ2, ZZ3, ZZ4, ZZ5, ZZ6, ZZ7)
#undef PIN8

    // ---- wave 3D bbox (TRUE min/max of this wave's points) ----
    float wxlo, wxhi, wylo, wyhi, wzlo, wzhi;
    {
        float mnx = fminf(XX0.x, XX0.y), mxx = fmaxf(XX0.x, XX0.y);
        float mny = fminf(YY0.x, YY0.y), mxy = fmaxf(YY0.x, YY0.y);
        float mnz = fminf(ZZ0.x, ZZ0.y), mxz = fmaxf(ZZ0.x, ZZ0.y);
#define MINMAX(j) { mnx = fminf(mnx, fminf(XX##j.x, XX##j.y)); \
                    mxx = fmaxf(mxx, fmaxf(XX##j.x, XX##j.y)); \
                    mny = fminf(mny, fminf(YY##j.x, YY##j.y)); \
                    mxy = fmaxf(mxy, fmaxf(YY##j.x, YY##j.y)); \
                    mnz = fminf(mnz, fminf(ZZ##j.x, ZZ##j.y)); \
                    mxz = fmaxf(mxz, fmaxf(ZZ##j.x, ZZ##j.y)); }
        MINMAX(1) MINMAX(2) MINMAX(3) MINMAX(4) MINMAX(5) MINMAX(6) MINMAX(7)
#undef MINMAX
        DPP_RED6(DPP_FMIN_STEP, mnx)
        DPP_RED6(DPP_FMAX_STEP, mxx)
        DPP_RED6(DPP_FMIN_STEP, mny)
        DPP_RED6(DPP_FMAX_STEP, mxy)
        DPP_RED6(DPP_FMIN_STEP, mnz)
        DPP_RED6(DPP_FMAX_STEP, mxz)
        wxlo = __int_as_float(__builtin_amdgcn_readlane(__float_as_int(mnx), 63));
        wxhi = __int_as_float(__builtin_amdgcn_readlane(__float_as_int(mxx), 63));
        wylo = __int_as_float(__builtin_amdgcn_readlane(__float_as_int(mny), 63));
        wyhi = __int_as_float(__builtin_amdgcn_readlane(__float_as_int(mxy), 63));
        wzlo = __int_as_float(__builtin_amdgcn_readlane(__float_as_int(mnz), 63));
        wzhi = __int_as_float(__builtin_amdgcn_readlane(__float_as_int(mxz), 63));
    }

    // ---- init dists to point 0 + lane-local argmax ----
    float bd = -1.0f;
    int   bk = 0;
#define INITP(j) { \
        v2f dx = XX##j - qx2; \
        v2f dy = YY##j - qy2; \
        v2f dz = ZZ##j - qz2; \
        v2f nd = (dx * dx + dy * dy) + dz * dz; \
        DD##j = nd; \
        if (nd.x > bd) { bd = nd.x; bk = 2*(j); } \
        if (nd.y > bd) { bd = nd.y; bk = 2*(j) + 1; } \
    }
    PAIRS8_X(INITP)
#undef INITP

    if (tid == 0) out[cloud * M] = base;   // first sample = point 0

    // ---- initial wave key (same as the loop's active path) ----
    u32 c_hi, c_lo;                        // cached wave key (uniform)
    {
        int bi;
        if constexpr (SORTED) bi = (int)mlds[(bk << 10) + tid];
        else                  bi = tid * PPT + bk;
        u64 key = ((u64)__float_as_uint(bd) << 32) | (u32)(~bi);
        DPP_MAX_STEP(key, 0x111)
        DPP_MAX_STEP(key, 0x112)
        DPP_MAX_STEP(key, 0x114)
        DPP_MAX_STEP(key, 0x118)
        DPP_MAX_STEP(key, 0x142)
        DPP_MAX_STEP(key, 0x143)
        c_hi = (u32)__builtin_amdgcn_readlane((int)(u32)(key >> 32), 63);
        c_lo = (u32)__builtin_amdgcn_readlane((int)(u32)key, 63);
    }

    for (int i = 1; i < M; ++i) {
        // ---- publish this wave's current best key (cached; always valid) ----
        if (lane == 0) skey[i & 1][wave] = ((u64)c_hi << 32) | c_lo;
        __syncthreads();

        // ---- cross-wave: lanes hold the 16 wave keys, 4 DPP steps, lane 15 ----
        u64 key2 = skey[i & 1][lane & 15];
        DPP_MAX_STEP(key2, 0x111)
        DPP_MAX_STEP(key2, 0x112)
        DPP_MAX_STEP(key2, 0x114)
        DPP_MAX_STEP(key2, 0x118)   // lane 15 = max of keys 0..15
        const u32 wlo = (u32)__builtin_amdgcn_readlane((int)(u32)key2, 15);
        const int wi  = (int)(~wlo);            // winner ORIGINAL local index

        if (tid == 0) out[cloud * M + i] = base + wi;

        // ---- fetch winner coords from ORIGINAL array (uniform -> s_load) ----
        const float* qp = pos + (size_t)(base + wi) * 3;
        const float qx = qp[0], qy = qp[1], qz = qp[2];

        // ---- wave-level exact 3D prune: skip iff bbox lower bound provably
        //      exceeds this wave's max min-dist (cached key hi) ----
        const float dxg = fmaxf(fmaxf(wxlo - qx, qx - wxhi), 0.0f);
        const float dyg = fmaxf(fmaxf(wylo - qy, qy - wyhi), 0.0f);
        const float dzg = fmaxf(fmaxf(wzlo - qz, qz - wzhi), 0.0f);
        const float lb  = (dxg * dxg + dyg * dyg + dzg * dzg) * 0.9999f;
        if (!(lb > __uint_as_float(c_hi))) {
            // ---- active: fused distance update + lane-local argmax ----
            qx2 = (v2f){qx, qx}; qy2 = (v2f){qy, qy}; qz2 = (v2f){qz, qz};
            bd = -1.0f; bk = 0;
#define UPD(j) { \
        v2f dx = XX##j - qx2; \
        v2f dy = YY##j - qy2; \
        v2f dz = ZZ##j - qz2; \
        v2f nd = (dx * dx + dy * dy) + dz * dz; \
        DD##j.x = fminf(DD##j.x, nd.x); \
        DD##j.y = fminf(DD##j.y, nd.y); \
        if (DD##j.x > bd) { bd = DD##j.x; bk = 2*(j); } \
        if (DD##j.y > bd) { bd = DD##j.y; bk = 2*(j) + 1; } \
    }
            PAIRS8_X(UPD)
#undef UPD
            int bi;
            if constexpr (SORTED) bi = (int)mlds[(bk << 10) + tid];
            else                  bi = tid * PPT + bk;
            u64 key = ((u64)__float_as_uint(bd) << 32) | (u32)(~bi);
            DPP_MAX_STEP(key, 0x111)
            DPP_MAX_STEP(key, 0x112)
            DPP_MAX_STEP(key, 0x114)
            DPP_MAX_STEP(key, 0x118)
            DPP_MAX_STEP(key, 0x142)
            DPP_MAX_STEP(key, 0x143)
            c_hi = (u32)__builtin_amdgcn_readlane((int)(u32)(key >> 32), 63);
            c_lo = (u32)__builtin_amdgcn_readlane((int)(u32)key, 63);
        }
        // skipped: DD/bd/bk/c_* unchanged -- provably identical to full update
    }
}

extern "C" void kernel_launch(void* const* d_in, const int* in_sizes, int n_in,
                              void* d_out, int out_size, void* d_ws, size_t ws_size,
                              hipStream_t stream) {
    const float* pos = (const float*)d_in[0];
    int* out = (int*)d_out;

    const size_t pos_s_bytes = (size_t)N_CLOUDS * PTS * 3 * sizeof(float);   // 3 MiB
    const size_t map_bytes   = (size_t)N_CLOUDS * PTS * sizeof(u16);         // 0.5 MiB
    if (d_ws && ws_size >= pos_s_bytes + map_bytes) {
        float* pos_s = (float*)d_ws;
        u16*   mapT  = (u16*)((char*)d_ws + pos_s_bytes);
        sort_kernel<<<N_CLOUDS, SORT_THREADS, 0, stream>>>(pos, pos_s, mapT);
        fps_kernel<true><<<N_CLOUDS, FPS_THREADS, 0, stream>>>(pos, pos_s, mapT, out);
    } else {
        fps_kernel<false><<<N_CLOUDS, FPS_THREADS, 0, stream>>>(pos, pos, nullptr, out);
    }
}

// Round 6
// 4400.478 us; speedup vs baseline: 1.2554x; 1.2554x over previous
//
#include <hip/hip_runtime.h>

#define N_CLOUDS 16
#define PTS      16384
#define M        4096
#define FPS_THREADS  1024
#define NWAVES   (FPS_THREADS / 64)   // 16 waves
#define PPT      16                   // consecutive (sorted-order) points per thread
#define SORT_THREADS 512

typedef float v2f __attribute__((ext_vector_type(2)));
typedef unsigned long long u64;
typedef unsigned int u32;
typedef unsigned short u16;

// Round-10 (resubmit; round-5 bench was an infra failure, not a kernel verdict):
// exact 3-level k-d partition + per-ROW (256-pt) prune bounds with wave skip.
//  - sort_kernel: bitonic by x (4 slabs of 4096) -> bitonic k<=4096 by y
//    (16 xy-columns of 1024 = one wave each) -> bitonic k<=1024 by z
//    (4 z-regions of 256/wave = one 16-lane DPP row each).
//    Morton (round-9) abandoned: equal-count Morton ranges straddle curve
//    discontinuities; one stray point blows up a min/max bbox -> no pruning
//    (measured A ~ 15.6/16). k-d boundaries never straddle.
//  - fps_kernel: per-row TRUE 3D bbox via in-row butterfly (quad_perm xor1,
//    xor2, row_half_mirror, row_mirror -- exact: sources are pair/quad/oct-
//    uniform by induction). Row maxDD falls out of the key reduce for free:
//    butterfly 4 steps (all 16 lanes = row max key), SAVE, then
//    row_bcast15/31 + readlane(63) for the wave key (proven chain).
//  - prune: lane tests ITS row's region (lb_row*0.9999 > rowMaxDD); wave
//    skips iff __all(...). Strictly stronger than wave-level test
//    (lb_r >= lb_wave, maxDD_r <= maxDD_wave); the sparse z-tail only
//    poisons ONE 256-pt region per column instead of the whole wave.
//  - exactness unchanged: skip only when every fminf(DD,nd) in all 4 regions
//    is a provable no-op (fp err ~4e-7 << 1e-4 margin); u64 key =
//    (dist_bits<<32)|~orig; per-16-chunk ascending-orig slots.

#define PAIRS8_X(X) X(0) X(1) X(2) X(3) X(4) X(5) X(6) X(7)

// u64 max-combine with DPP-shifted copy (old=0 is identity: keys >= 0)
#define DPP_MAX_STEP(key, CTRL) { \
        const u32 lo_  = (u32)(key); \
        const u32 hi_  = (u32)((key) >> 32); \
        const u32 lo2_ = (u32)__builtin_amdgcn_update_dpp(0, (int)lo_, (CTRL), 0xf, 0xf, false); \
        const u32 hi2_ = (u32)__builtin_amdgcn_update_dpp(0, (int)hi_, (CTRL), 0xf, 0xf, false); \
        const u64 ok_  = ((u64)hi2_ << 32) | lo2_; \
        (key) = (ok_ > (key)) ? ok_ : (key); \
    }

// float min/max combine with DPP copy (old = own value)
#define DPP_FMIN_STEP(v, CTRL) { \
        const int t_ = __builtin_amdgcn_update_dpp(__float_as_int(v), __float_as_int(v), (CTRL), 0xf, 0xf, false); \
        (v) = fminf((v), __int_as_float(t_)); \
    }
#define DPP_FMAX_STEP(v, CTRL) { \
        const int t_ = __builtin_amdgcn_update_dpp(__float_as_int(v), __float_as_int(v), (CTRL), 0xf, 0xf, false); \
        (v) = fmaxf((v), __int_as_float(t_)); \
    }
// full-wave (used in sort kernel)
#define DPP_RED6(MACRO, v) \
        MACRO(v, 0x111) MACRO(v, 0x112) MACRO(v, 0x114) MACRO(v, 0x118) \
        MACRO(v, 0x142) MACRO(v, 0x143)
// in-row butterfly all-reduce: xor1, xor2, then mirrors (exact on quad-/oct-
// uniform values) -> ALL 16 lanes of each row hold the row result
#define DPP_BFLY4(MACRO, v) \
        MACRO(v, 0xB1) MACRO(v, 0x4E) MACRO(v, 0x141) MACRO(v, 0x140)

// ---------------------------------------------------------------------------
// One-time spatial ordering kernel: one block per cloud.
// 3 bitonic passes (x full, y within 4096-groups, z within 1024-groups) ->
// exact equal-count k-d tiles: wave = xy-column of 1024, row = z-quarter of
// 256. Then per-16-chunk ascending-orig re-sort (exact first-occurrence tie
// semantics) and emit reordered coords + slot-major u16 map [16][1024].
// fps correctness does NOT depend on sort quality (map is a permutation).
// ---------------------------------------------------------------------------
#define BITONIC_PASS(KMAX) \
    for (u32 k = 2; k <= (u32)(KMAX); k <<= 1) { \
        for (u32 j = k >> 1; j; j >>= 1) { \
            __syncthreads(); \
            for (int s = 0; s < PTS / SORT_THREADS; ++s) { \
                const u32 i = (u32)(tid + s * SORT_THREADS); \
                const u32 p = i ^ j; \
                if (p > i) { \
                    const u32 a = keys[i], b = keys[p]; \
                    if (((i & k) == 0) == (a > b)) { keys[i] = b; keys[p] = a; } \
                } \
            } \
        } \
    } \
    __syncthreads();

__global__ __launch_bounds__(SORT_THREADS)
void sort_kernel(const float* __restrict__ pos, float* __restrict__ pos_s,
                 u16* __restrict__ mapT)
{
    __shared__ u32 keys[PTS];          // 64 KiB
    const int cloud = blockIdx.x;
    const int tid   = threadIdx.x;
    const int ln    = tid & 63;
    const size_t b3 = (size_t)cloud * PTS * 3;

    // ---- x/y/z ranges of this cloud ----
    float mnx = 1e30f, mxx = -1e30f, mny = 1e30f, mxy = -1e30f;
    float mnz = 1e30f, mxz = -1e30f;
    for (int s = 0; s < PTS / SORT_THREADS; ++s) {
        const size_t o = b3 + (size_t)(tid + s * SORT_THREADS) * 3;
        const float x = pos[o + 0];
        const float y = pos[o + 1];
        const float z = pos[o + 2];
        mnx = fminf(mnx, x); mxx = fmaxf(mxx, x);
        mny = fminf(mny, y); mxy = fmaxf(mxy, y);
        mnz = fminf(mnz, z); mxz = fmaxf(mxz, z);
    }
    DPP_RED6(DPP_FMIN_STEP, mnx)
    DPP_RED6(DPP_FMAX_STEP, mxx)
    DPP_RED6(DPP_FMIN_STEP, mny)
    DPP_RED6(DPP_FMAX_STEP, mxy)
    DPP_RED6(DPP_FMIN_STEP, mnz)
    DPP_RED6(DPP_FMAX_STEP, mxz)
    float* red = (float*)keys;         // reuse LDS before keys are written
    const int nw = SORT_THREADS / 64;
    if (ln == 63) {
        red[tid >> 6]          = mnx;
        red[nw + (tid >> 6)]   = mxx;
        red[2*nw + (tid >> 6)] = mny;
        red[3*nw + (tid >> 6)] = mxy;
        red[4*nw + (tid >> 6)] = mnz;
        red[5*nw + (tid >> 6)] = mxz;
    }
    __syncthreads();
    float xmin = red[0], xmax = red[nw], ymin = red[2*nw], ymax = red[3*nw];
    float zmin = red[4*nw], zmax = red[5*nw];
    for (int w = 1; w < nw; ++w) {
        xmin = fminf(xmin, red[w]);
        xmax = fmaxf(xmax, red[nw + w]);
        ymin = fminf(ymin, red[2*nw + w]);
        ymax = fmaxf(ymax, red[3*nw + w]);
        zmin = fminf(zmin, red[4*nw + w]);
        zmax = fmaxf(zmax, red[5*nw + w]);
    }
    __syncthreads();

    const float xscale = 262143.0f / fmaxf(xmax - xmin, 1e-30f);
    const float yscale = 262143.0f / fmaxf(ymax - ymin, 1e-30f);
    const float zscale = 262143.0f / fmaxf(zmax - zmin, 1e-30f);

    // ---- pass A: key by quantized x | orig ----
    for (int s = 0; s < PTS / SORT_THREADS; ++s) {
        const int i = tid + s * SORT_THREADS;
        const float x = pos[b3 + (size_t)i * 3];
        const u32 q = (u32)fminf(fmaxf((x - xmin) * xscale, 0.0f), 262143.0f);
        keys[i] = (q << 14) | (u32)i;
    }
    BITONIC_PASS(PTS)

    // ---- pass B: rekey by y, sort within 4096-groups ----
    for (int s = 0; s < PTS / SORT_THREADS; ++s) {
        const int i = tid + s * SORT_THREADS;
        const u32 orig = keys[i] & (u32)(PTS - 1);
        const float y = pos[b3 + (size_t)orig * 3 + 1];
        const u32 q = (u32)fminf(fmaxf((y - ymin) * yscale, 0.0f), 262143.0f);
        keys[i] = (q << 14) | orig;
    }
    BITONIC_PASS(4096u)

    // ---- pass C: rekey by z, sort within 1024-groups ----
    for (int s = 0; s < PTS / SORT_THREADS; ++s) {
        const int i = tid + s * SORT_THREADS;
        const u32 orig = keys[i] & (u32)(PTS - 1);
        const float z = pos[b3 + (size_t)orig * 3 + 2];
        const u32 q = (u32)fminf(fmaxf((z - zmin) * zscale, 0.0f), 262143.0f);
        keys[i] = (q << 14) | orig;
    }
    BITONIC_PASS(1024u)

    // ---- within each 16-chunk (one fps thread's slots), re-sort ascending
    //      by ORIGINAL index -> exact first-occurrence tie semantics ----
    for (int c = 0; c < 2; ++c) {
        u32 loc[PPT];
        const int cb = tid * 32 + c * PPT;
        for (int s = 0; s < PPT; ++s) loc[s] = keys[cb + s] & (u32)(PTS - 1);
        for (int a = 1; a < PPT; ++a) {
            const u32 v = loc[a];
            int b = a;
            while (b > 0 && loc[b - 1] > v) { loc[b] = loc[b - 1]; --b; }
            loc[b] = v;
        }
        for (int s = 0; s < PPT; ++s) keys[cb + s] = loc[s];
    }
    __syncthreads();

    // ---- emit reordered coords (bit-copies) + slot-major map [16][1024] ----
    for (int s = 0; s < PTS / SORT_THREADS; ++s) {
        const int i = tid + s * SORT_THREADS;   // sorted position
        const u32 orig = keys[i];
        mapT[(size_t)cloud * PTS + (size_t)(i & (PPT - 1)) * FPS_THREADS + (i >> 4)] = (u16)orig;
        const size_t so = b3 + (size_t)i * 3;
        const size_t oo = b3 + (size_t)orig * 3;
        pos_s[so + 0] = pos[oo + 0];
        pos_s[so + 1] = pos[oo + 1];
        pos_s[so + 2] = pos[oo + 2];
    }
}

// ---------------------------------------------------------------------------
// Main FPS kernel (one block per cloud, 16 waves). SORTED=false fallback.
// ---------------------------------------------------------------------------
// wave reduce: butterfly-in-row (saves row max key to rkhi/rklo in ALL 16
// lanes of the row), then bcast15/31 + readlane(63) for the wave max.
#define WAVE_REDUCE(key, rkhi, rklo, chi, clo) { \
        DPP_MAX_STEP(key, 0xB1)  /* quad_perm xor1  */ \
        DPP_MAX_STEP(key, 0x4E)  /* quad_perm xor2  */ \
        DPP_MAX_STEP(key, 0x141) /* row_half_mirror */ \
        DPP_MAX_STEP(key, 0x140) /* row_mirror      */ \
        rkhi = (u32)((key) >> 32); \
        rklo = (u32)(key); \
        DPP_MAX_STEP(key, 0x142) /* row_bcast15 */ \
        DPP_MAX_STEP(key, 0x143) /* row_bcast31 */ \
        chi = (u32)__builtin_amdgcn_readlane((int)(u32)((key) >> 32), 63); \
        clo = (u32)__builtin_amdgcn_readlane((int)(u32)(key), 63); \
    }

template<bool SORTED>
__global__ __launch_bounds__(FPS_THREADS)
__attribute__((amdgpu_waves_per_eu(4, 4)))
void fps_kernel(const float* __restrict__ pos,      // original (winner fetch, q0)
                const float* __restrict__ psrc,     // sorted coords (or == pos)
                const u16* __restrict__ mapT,       // slot-major orig map (or null)
                int* __restrict__ out)
{
#pragma clang fp contract(off)
    const int cloud = blockIdx.x;
    const int tid   = threadIdx.x;
    const int base  = cloud * PTS;
    const int wave  = tid >> 6;
    const int lane  = tid & 63;

    __shared__ u64 skey[2][NWAVES];
    __shared__ __attribute__((aligned(16))) u16 mlds[PTS];   // [slot][thread]

    if constexpr (SORTED) {
        // stage orig-index map into LDS (coalesced uint4 copy)
        const uint4* src = (const uint4*)(mapT + (size_t)cloud * PTS);
        uint4* dst = (uint4*)mlds;
#pragma unroll
        for (int s = 0; s < PTS * 2 / 16 / FPS_THREADS; ++s)   // 2 iters
            dst[s * FPS_THREADS + tid] = src[s * FPS_THREADS + tid];
        __syncthreads();
    }

    // ---- query = point 0 of cloud (ORIGINAL order) ----
    const float q0x = pos[(size_t)base * 3 + 0];
    const float q0y = pos[(size_t)base * 3 + 1];
    const float q0z = pos[(size_t)base * 3 + 2];
    v2f qx2 = {q0x, q0x}, qy2 = {q0y, q0y}, qz2 = {q0z, q0z};

    // ---- one-time vectorized load: 16 consecutive pts = 12 float4,
    //      loaded per-quad (3 float4 -> 6 v2f) to cap VGPR pressure ----
    const float4* pos4 = (const float4*)psrc;
    const int fo = cloud * (PTS * 3 / 4) + tid * (PPT * 3 / 4);   // 12 f4/thread

#define DECL(j) v2f XX##j, YY##j, ZZ##j, DD##j;
    PAIRS8_X(DECL)
#undef DECL

#define QUADLOAD(q, j0, j1) { \
        const float4 fa = pos4[fo + 3*(q) + 0]; \
        const float4 fb = pos4[fo + 3*(q) + 1]; \
        const float4 fc = pos4[fo + 3*(q) + 2]; \
        XX##j0 = (v2f){fa.x, fa.w}; \
        YY##j0 = (v2f){fa.y, fb.x}; \
        ZZ##j0 = (v2f){fa.z, fb.y}; \
        XX##j1 = (v2f){fb.z, fc.y}; \
        YY##j1 = (v2f){fb.w, fc.z}; \
        ZZ##j1 = (v2f){fc.x, fc.w}; }
    QUADLOAD(0, 0, 1) QUADLOAD(1, 2, 3) QUADLOAD(2, 4, 5) QUADLOAD(3, 6, 7)
#undef QUADLOAD

    // ---- pin coords in VGPRs: opaque defs => no remat, no reload ----
#define PIN8(a,b,c,d,e,g,h,k) asm volatile("" : "+v"(a),"+v"(b),"+v"(c),"+v"(d),"+v"(e),"+v"(g),"+v"(h),"+v"(k));
    PIN8(XX0, XX1, XX2, XX3, XX4, XX5, XX6, XX7)
    PIN8(YY0, YY1, YY2, YY3, YY4, YY5, YY6, YY7)
    PIN8(ZZ0, ZZ1, ZZ2, ZZ3, ZZ4, ZZ5, ZZ6, ZZ7)
#undef PIN8

    // ---- per-ROW (16-lane = 256-pt region) TRUE 3D bbox, held per-lane ----
    float rxlo, rxhi, rylo, ryhi, rzlo, rzhi;
    {
        float mnx = fminf(XX0.x, XX0.y), mxx = fmaxf(XX0.x, XX0.y);
        float mny = fminf(YY0.x, YY0.y), mxy = fmaxf(YY0.x, YY0.y);
        float mnz = fminf(ZZ0.x, ZZ0.y), mxz = fmaxf(ZZ0.x, ZZ0.y);
#define MINMAX(j) { mnx = fminf(mnx, fminf(XX##j.x, XX##j.y)); \
                    mxx = fmaxf(mxx, fmaxf(XX##j.x, XX##j.y)); \
                    mny = fminf(mny, fminf(YY##j.x, YY##j.y)); \
                    mxy = fmaxf(mxy, fmaxf(YY##j.x, YY##j.y)); \
                    mnz = fminf(mnz, fminf(ZZ##j.x, ZZ##j.y)); \
                    mxz = fmaxf(mxz, fmaxf(ZZ##j.x, ZZ##j.y)); }
        MINMAX(1) MINMAX(2) MINMAX(3) MINMAX(4) MINMAX(5) MINMAX(6) MINMAX(7)
#undef MINMAX
        DPP_BFLY4(DPP_FMIN_STEP, mnx)
        DPP_BFLY4(DPP_FMAX_STEP, mxx)
        DPP_BFLY4(DPP_FMIN_STEP, mny)
        DPP_BFLY4(DPP_FMAX_STEP, mxy)
        DPP_BFLY4(DPP_FMIN_STEP, mnz)
        DPP_BFLY4(DPP_FMAX_STEP, mxz)
        rxlo = mnx; rxhi = mxx; rylo = mny; ryhi = mxy; rzlo = mnz; rzhi = mxz;
    }

    // ---- init dists to point 0 + lane-local argmax ----
    float bd = -1.0f;
    int   bk = 0;
#define INITP(j) { \
        v2f dx = XX##j - qx2; \
        v2f dy = YY##j - qy2; \
        v2f dz = ZZ##j - qz2; \
        v2f nd = (dx * dx + dy * dy) + dz * dz; \
        DD##j = nd; \
        if (nd.x > bd) { bd = nd.x; bk = 2*(j); } \
        if (nd.y > bd) { bd = nd.y; bk = 2*(j) + 1; } \
    }
    PAIRS8_X(INITP)
#undef INITP

    if (tid == 0) out[cloud * M] = base;   // first sample = point 0

    // ---- initial reduce: row key (rk, per-lane row-uniform) + wave key ----
    u32 rk_hi, rk_lo, c_hi, c_lo;
    {
        int bi;
        if constexpr (SORTED) bi = (int)mlds[(bk << 10) + tid];
        else                  bi = tid * PPT + bk;
        u64 key = ((u64)__float_as_uint(bd) << 32) | (u32)(~bi);
        WAVE_REDUCE(key, rk_hi, rk_lo, c_hi, c_lo)
    }

    for (int i = 1; i < M; ++i) {
        // ---- publish this wave's current best key (cached; always valid) ----
        if (lane == 0) skey[i & 1][wave] = ((u64)c_hi << 32) | c_lo;
        __syncthreads();

        // ---- cross-wave: lanes hold the 16 wave keys, 4 DPP steps, lane 15 ----
        u64 key2 = skey[i & 1][lane & 15];
        DPP_MAX_STEP(key2, 0x111)
        DPP_MAX_STEP(key2, 0x112)
        DPP_MAX_STEP(key2, 0x114)
        DPP_MAX_STEP(key2, 0x118)   // lane 15 = max of keys 0..15
        const u32 wlo = (u32)__builtin_amdgcn_readlane((int)(u32)key2, 15);
        const int wi  = (int)(~wlo);            // winner ORIGINAL local index

        if (tid == 0) out[cloud * M + i] = base + wi;

        // ---- fetch winner coords from ORIGINAL array (uniform -> s_load) ----
        const float* qp = pos + (size_t)(base + wi) * 3;
        const float qx = qp[0], qy = qp[1], qz = qp[2];

        // ---- per-row exact prune: lane tests ITS row's 256-pt region;
        //      wave skips iff ALL rows provably unaffected ----
        const float dxg = fmaxf(fmaxf(rxlo - qx, qx - rxhi), 0.0f);
        const float dyg = fmaxf(fmaxf(rylo - qy, qy - ryhi), 0.0f);
        const float dzg = fmaxf(fmaxf(rzlo - qz, qz - rzhi), 0.0f);
        const float lb  = (dxg * dxg + dyg * dyg + dzg * dzg) * 0.9999f;
        if (!__all(lb > __uint_as_float(rk_hi))) {
            // ---- active: fused distance update + lane-local argmax ----
            qx2 = (v2f){qx, qx}; qy2 = (v2f){qy, qy}; qz2 = (v2f){qz, qz};
            bd = -1.0f; bk = 0;
#define UPD(j) { \
        v2f dx = XX##j - qx2; \
        v2f dy = YY##j - qy2; \
        v2f dz = ZZ##j - qz2; \
        v2f nd = (dx * dx + dy * dy) + dz * dz; \
        DD##j.x = fminf(DD##j.x, nd.x); \
        DD##j.y = fminf(DD##j.y, nd.y); \
        if (DD##j.x > bd) { bd = DD##j.x; bk = 2*(j); } \
        if (DD##j.y > bd) { bd = DD##j.y; bk = 2*(j) + 1; } \
    }
            PAIRS8_X(UPD)
#undef UPD
            int bi;
            if constexpr (SORTED) bi = (int)mlds[(bk << 10) + tid];
            else                  bi = tid * PPT + bk;
            u64 key = ((u64)__float_as_uint(bd) << 32) | (u32)(~bi);
            WAVE_REDUCE(key, rk_hi, rk_lo, c_hi, c_lo)
        }
        // skipped: DD/bd/bk/rk/c unchanged -- provably identical to full update
    }
}

extern "C" void kernel_launch(void* const* d_in, const int* in_sizes, int n_in,
                              void* d_out, int out_size, void* d_ws, size_t ws_size,
                              hipStream_t stream) {
    const float* pos = (const float*)d_in[0];
    int* out = (int*)d_out;

    const size_t pos_s_bytes = (size_t)N_CLOUDS * PTS * 3 * sizeof(float);   // 3 MiB
    const size_t map_bytes   = (size_t)N_CLOUDS * PTS * sizeof(u16);         // 0.5 MiB
    if (d_ws && ws_size >= pos_s_bytes + map_bytes) {
        float* pos_s = (float*)d_ws;
        u16*   mapT  = (u16*)((char*)d_ws + pos_s_bytes);
        sort_kernel<<<N_CLOUDS, SORT_THREADS, 0, stream>>>(pos, pos_s, mapT);
        fps_kernel<true><<<N_CLOUDS, FPS_THREADS, 0, stream>>>(pos, pos_s, mapT, out);
    } else {
        fps_kernel<false><<<N_CLOUDS, FPS_THREADS, 0, stream>>>(pos, pos, nullptr, out);
    }
}